// Round 1
// 511.979 us; speedup vs baseline: 1.0064x; 1.0064x over previous
//
#include <hip/hip_runtime.h>

#define NBATCH 16
#define NCH 64
#define CPG 4
#define NGRP 16
#define EPSV 1e-5f

// ws layout (bytes):
//   0     : S1  [16][64] float  (4096)
//   4096  : S2  [16][64] float  (4096)
//   8192  : cnt [16] int        (64)   -- zeroed region ends at 8256

// ---------------------------------------------------------------------------
// Pass 1: per-segment sum / sum-of-squares / count.
// 2048 blocks (8/CU -> 8 waves/SIMD) and 4x-unrolled row loop: 4 float4 loads
// + 4 bid loads issued back-to-back before use -> 4x MLP vs previous version.
// batch_id is sorted, so the all-same-segment fast path dominates.
// ---------------------------------------------------------------------------
__global__ void ogn_stats(const float* __restrict__ data,
                          const int* __restrict__ bid,
                          float* __restrict__ S1,
                          float* __restrict__ S2,
                          int* __restrict__ cnt,
                          int N, int rows_per_block) {
    __shared__ float ls1[NBATCH * NCH];
    __shared__ float ls2[NBATCH * NCH];
    __shared__ int   lcnt[NBATCH];

    for (int i = threadIdx.x; i < NBATCH * NCH; i += blockDim.x) {
        ls1[i] = 0.f;
        ls2[i] = 0.f;
    }
    if (threadIdx.x < NBATCH) lcnt[threadIdx.x] = 0;
    __syncthreads();

    const int t     = threadIdx.x;
    const int c4    = t & 15;   // which float4 of the 64-ch row
    const int rlane = t >> 4;   // 0..15: row within a 16-row sweep

    long long row_begin = (long long)blockIdx.x * rows_per_block;
    long long row_end   = row_begin + rows_per_block;
    if (row_end > N) row_end = N;

    const float4* data4 = (const float4*)data;

    float4 s1 = make_float4(0.f, 0.f, 0.f, 0.f);
    float4 s2 = make_float4(0.f, 0.f, 0.f, 0.f);
    int cur = -1;
    int c   = 0;

#define FLUSH() do { if (cur >= 0) {                                   \
        int base_ = cur * NCH + c4 * 4;                                \
        atomicAdd(&ls1[base_ + 0], s1.x);                              \
        atomicAdd(&ls1[base_ + 1], s1.y);                              \
        atomicAdd(&ls1[base_ + 2], s1.z);                              \
        atomicAdd(&ls1[base_ + 3], s1.w);                              \
        atomicAdd(&ls2[base_ + 0], s2.x);                              \
        atomicAdd(&ls2[base_ + 1], s2.y);                              \
        atomicAdd(&ls2[base_ + 2], s2.z);                              \
        atomicAdd(&ls2[base_ + 3], s2.w);                              \
        if (c4 == 0) atomicAdd(&lcnt[cur], c);                         \
    } } while (0)

#define ACCV(vv) do {                                                  \
        s1.x += (vv).x; s1.y += (vv).y; s1.z += (vv).z; s1.w += (vv).w;\
        s2.x = fmaf((vv).x, (vv).x, s2.x);                             \
        s2.y = fmaf((vv).y, (vv).y, s2.y);                             \
        s2.z = fmaf((vv).z, (vv).z, s2.z);                             \
        s2.w = fmaf((vv).w, (vv).w, s2.w);                             \
    } while (0)

#define ACC1(bb, vv) do {                                              \
        if ((bb) != cur) {                                             \
            FLUSH();                                                   \
            s1 = make_float4(0.f, 0.f, 0.f, 0.f);                      \
            s2 = make_float4(0.f, 0.f, 0.f, 0.f);                      \
            c = 0; cur = (bb);                                         \
        }                                                              \
        ACCV(vv); c++;                                                 \
    } while (0)

    long long r = row_begin + rlane;

    // 4x unrolled main loop: issue all loads first (MLP), then accumulate.
    for (; r + 48 < row_end; r += 64) {
        int b0 = bid[r];
        int b1 = bid[r + 16];
        int b2 = bid[r + 32];
        int b3 = bid[r + 48];
        float4 v0 = data4[r * 16 + c4];
        float4 v1 = data4[(r + 16) * 16 + c4];
        float4 v2 = data4[(r + 32) * 16 + c4];
        float4 v3 = data4[(r + 48) * 16 + c4];
        if (((b0 == cur) & (b1 == cur) & (b2 == cur) & (b3 == cur)) != 0) {
            // fast path: all four rows in the current segment
            ACCV(v0); ACCV(v1); ACCV(v2); ACCV(v3);
            c += 4;
        } else {
            ACC1(b0, v0);
            ACC1(b1, v1);
            ACC1(b2, v2);
            ACC1(b3, v3);
        }
    }
    // remainder rows
    for (; r < row_end; r += 16) {
        int b = bid[r];
        float4 v = data4[r * 16 + c4];
        ACC1(b, v);
    }
    FLUSH();
    __syncthreads();

    for (int i = threadIdx.x; i < NBATCH * NCH; i += blockDim.x) {
        float v1 = ls1[i];
        float v2 = ls2[i];
        if (v1 != 0.f) atomicAdd(&S1[i], v1);
        if (v2 != 0.f) atomicAdd(&S2[i], v2);
    }
    if (threadIdx.x < NBATCH) {
        int v = lcnt[threadIdx.x];
        if (v != 0) atomicAdd(&cnt[threadIdx.x], v);
    }

#undef ACC1
#undef ACCV
#undef FLUSH
}

// ---------------------------------------------------------------------------
// Pass 2: fused params + apply.
// Prologue: the 256 threads of each block compute the 16x16 (batch,group)
// A/B table from S1/S2/cnt (L2-hot, ~8.5 KB) directly into LDS. This removes
// the single-block ogn_params launch (a whole-GPU serialization point) and
// turns the hot loop's dependent chain from bid->global into bid->ds_read.
// ---------------------------------------------------------------------------
__global__ void ogn_apply(const float* __restrict__ data,
                          const int* __restrict__ bid,
                          const float* __restrict__ S1,
                          const float* __restrict__ S2,
                          const int* __restrict__ cnt,
                          const float* __restrict__ w,
                          const float* __restrict__ bias,
                          float* __restrict__ out,
                          long long total4) {
    __shared__ float4 lA[NBATCH * NGRP];
    __shared__ float4 lB[NBATCH * NGRP];

    const int t = threadIdx.x;
    if (t < NBATCH * NGRP) {
        int b = t >> 4;        // batch
        int g = t & 15;        // group == float4 chunk (CPG == 4)
        int base = b * NCH + g * CPG;
        float s1g = 0.f, s2g = 0.f;
#pragma unroll
        for (int k = 0; k < CPG; ++k) {
            s1g += S1[base + k];
            s2g += S2[base + k];
        }
        float countf    = (float)cnt[b] * (float)CPG;
        float inv_count = 1.f / (countf + EPSV);
        float mean      = s1g * inv_count;
        float var       = inv_count * (s2g - 2.f * mean * s1g + countf * mean * mean);
        float inv_std   = rsqrtf(var + EPSV);

        float4 wv = ((const float4*)w)[g];
        float4 bv = ((const float4*)bias)[g];
        float4 a4, b4;
        a4.x = inv_std * wv.x; b4.x = bv.x - mean * a4.x;
        a4.y = inv_std * wv.y; b4.y = bv.y - mean * a4.y;
        a4.z = inv_std * wv.z; b4.z = bv.z - mean * a4.z;
        a4.w = inv_std * wv.w; b4.w = bv.w - mean * a4.w;
        lA[b * NGRP + g] = a4;
        lB[b * NGRP + g] = b4;
    }
    __syncthreads();

    const float4* d4 = (const float4*)data;
    float4* o4 = (float4*)out;

    long long i      = (long long)blockIdx.x * blockDim.x + threadIdx.x;
    long long stride = (long long)gridDim.x * blockDim.x;

    for (; i < total4; i += stride) {
        long long row = i >> 4;
        int c4 = (int)(i & 15);
        int b  = bid[row];
        float4 v  = d4[i];
        float4 a  = lA[b * NGRP + c4];
        float4 bb = lB[b * NGRP + c4];
        float4 r;
        r.x = fmaf(v.x, a.x, bb.x);
        r.y = fmaf(v.y, a.y, bb.y);
        r.z = fmaf(v.z, a.z, bb.z);
        r.w = fmaf(v.w, a.w, bb.w);
        o4[i] = r;
    }
}

extern "C" void kernel_launch(void* const* d_in, const int* in_sizes, int n_in,
                              void* d_out, int out_size, void* d_ws, size_t ws_size,
                              hipStream_t stream) {
    const float* data = (const float*)d_in[0];
    const int*   bid  = (const int*)d_in[1];
    const float* w    = (const float*)d_in[2];
    const float* bias = (const float*)d_in[3];
    float* out = (float*)d_out;

    int N = in_sizes[1];  // batch_id count

    char* ws = (char*)d_ws;
    float* S1  = (float*)(ws + 0);
    float* S2  = (float*)(ws + 4096);
    int*   cnt = (int*)  (ws + 8192);

    // zero the accumulator region (S1, S2, cnt)
    hipMemsetAsync(d_ws, 0, 8256, stream);

    const int NB1 = 2048;  // 8 blocks/CU -> 8 waves/SIMD occupancy
    int rows_per_block = (N + NB1 - 1) / NB1;
    ogn_stats<<<NB1, 256, 0, stream>>>(data, bid, S1, S2, cnt, N, rows_per_block);

    long long total4 = (long long)N * (NCH / 4);
    const int NB3 = 4096;
    ogn_apply<<<NB3, 256, 0, stream>>>(data, bid, S1, S2, cnt, w, bias, out, total4);
}

// Round 2
// 501.994 us; speedup vs baseline: 1.0264x; 1.0199x over previous
//
#include <hip/hip_runtime.h>

#define NBATCH 16
#define NCH 64
#define CPG 4
#define NGRP 16
#define EPSV 1e-5f

typedef float f32x4 __attribute__((ext_vector_type(4)));

// ws layout (bytes):
//   0     : S1  [16][64] float  (4096)
//   4096  : S2  [16][64] float  (4096)
//   8192  : cnt [16] int        (64)   -- zeroed region ends at 8256

// ---------------------------------------------------------------------------
// Pass 1: per-segment sum / sum-of-squares / count. BW-bound (verified: the
// R1 occupancy/unroll change was a null -> latency already hidden by TLP).
// Sweeps FORWARD so the data tail is L3-resident when pass 2 starts.
// ---------------------------------------------------------------------------
__global__ void ogn_stats(const float* __restrict__ data,
                          const int* __restrict__ bid,
                          float* __restrict__ S1,
                          float* __restrict__ S2,
                          int* __restrict__ cnt,
                          int N, int rows_per_block) {
    __shared__ float ls1[NBATCH * NCH];
    __shared__ float ls2[NBATCH * NCH];
    __shared__ int   lcnt[NBATCH];

    for (int i = threadIdx.x; i < NBATCH * NCH; i += blockDim.x) {
        ls1[i] = 0.f;
        ls2[i] = 0.f;
    }
    if (threadIdx.x < NBATCH) lcnt[threadIdx.x] = 0;
    __syncthreads();

    const int t     = threadIdx.x;
    const int c4    = t & 15;   // which float4 of the 64-ch row
    const int rlane = t >> 4;   // 0..15: row within a 16-row sweep

    long long row_begin = (long long)blockIdx.x * rows_per_block;
    long long row_end   = row_begin + rows_per_block;
    if (row_end > N) row_end = N;

    const float4* data4 = (const float4*)data;

    float4 s1 = make_float4(0.f, 0.f, 0.f, 0.f);
    float4 s2 = make_float4(0.f, 0.f, 0.f, 0.f);
    int cur = -1;
    int c   = 0;

#define FLUSH() do { if (cur >= 0) {                                   \
        int base_ = cur * NCH + c4 * 4;                                \
        atomicAdd(&ls1[base_ + 0], s1.x);                              \
        atomicAdd(&ls1[base_ + 1], s1.y);                              \
        atomicAdd(&ls1[base_ + 2], s1.z);                              \
        atomicAdd(&ls1[base_ + 3], s1.w);                              \
        atomicAdd(&ls2[base_ + 0], s2.x);                              \
        atomicAdd(&ls2[base_ + 1], s2.y);                              \
        atomicAdd(&ls2[base_ + 2], s2.z);                              \
        atomicAdd(&ls2[base_ + 3], s2.w);                              \
        if (c4 == 0) atomicAdd(&lcnt[cur], c);                         \
    } } while (0)

#define ACCV(vv) do {                                                  \
        s1.x += (vv).x; s1.y += (vv).y; s1.z += (vv).z; s1.w += (vv).w;\
        s2.x = fmaf((vv).x, (vv).x, s2.x);                             \
        s2.y = fmaf((vv).y, (vv).y, s2.y);                             \
        s2.z = fmaf((vv).z, (vv).z, s2.z);                             \
        s2.w = fmaf((vv).w, (vv).w, s2.w);                             \
    } while (0)

#define ACC1(bb, vv) do {                                              \
        if ((bb) != cur) {                                             \
            FLUSH();                                                   \
            s1 = make_float4(0.f, 0.f, 0.f, 0.f);                      \
            s2 = make_float4(0.f, 0.f, 0.f, 0.f);                      \
            c = 0; cur = (bb);                                         \
        }                                                              \
        ACCV(vv); c++;                                                 \
    } while (0)

    long long r = row_begin + rlane;

    for (; r + 48 < row_end; r += 64) {
        int b0 = bid[r];
        int b1 = bid[r + 16];
        int b2 = bid[r + 32];
        int b3 = bid[r + 48];
        float4 v0 = data4[r * 16 + c4];
        float4 v1 = data4[(r + 16) * 16 + c4];
        float4 v2 = data4[(r + 32) * 16 + c4];
        float4 v3 = data4[(r + 48) * 16 + c4];
        if (((b0 == cur) & (b1 == cur) & (b2 == cur) & (b3 == cur)) != 0) {
            ACCV(v0); ACCV(v1); ACCV(v2); ACCV(v3);
            c += 4;
        } else {
            ACC1(b0, v0);
            ACC1(b1, v1);
            ACC1(b2, v2);
            ACC1(b3, v3);
        }
    }
    for (; r < row_end; r += 16) {
        int b = bid[r];
        float4 v = data4[r * 16 + c4];
        ACC1(b, v);
    }
    FLUSH();
    __syncthreads();

    for (int i = threadIdx.x; i < NBATCH * NCH; i += blockDim.x) {
        float v1 = ls1[i];
        float v2 = ls2[i];
        if (v1 != 0.f) atomicAdd(&S1[i], v1);
        if (v2 != 0.f) atomicAdd(&S2[i], v2);
    }
    if (threadIdx.x < NBATCH) {
        int v = lcnt[threadIdx.x];
        if (v != 0) atomicAdd(&cnt[threadIdx.x], v);
    }

#undef ACC1
#undef ACCV
#undef FLUSH
}

// ---------------------------------------------------------------------------
// Pass 2: fused params + apply.
// Prologue computes the 16x16 (batch,group) A/B table into LDS.
// Hot loop sweeps BACKWARD (j = total4-1-i) so its first reads hit the
// L3-resident tail that pass 1 just produced, and uses NON-TEMPORAL stores
// for `out` so the write stream doesn't evict data lines still to be read.
// ---------------------------------------------------------------------------
__global__ void ogn_apply(const float* __restrict__ data,
                          const int* __restrict__ bid,
                          const float* __restrict__ S1,
                          const float* __restrict__ S2,
                          const int* __restrict__ cnt,
                          const float* __restrict__ w,
                          const float* __restrict__ bias,
                          float* __restrict__ out,
                          long long total4) {
    __shared__ float4 lA[NBATCH * NGRP];
    __shared__ float4 lB[NBATCH * NGRP];

    const int t = threadIdx.x;
    if (t < NBATCH * NGRP) {
        int b = t >> 4;        // batch
        int g = t & 15;        // group == float4 chunk (CPG == 4)
        int base = b * NCH + g * CPG;
        float s1g = 0.f, s2g = 0.f;
#pragma unroll
        for (int k = 0; k < CPG; ++k) {
            s1g += S1[base + k];
            s2g += S2[base + k];
        }
        float countf    = (float)cnt[b] * (float)CPG;
        float inv_count = 1.f / (countf + EPSV);
        float mean      = s1g * inv_count;
        float var       = inv_count * (s2g - 2.f * mean * s1g + countf * mean * mean);
        float inv_std   = rsqrtf(var + EPSV);

        float4 wv = ((const float4*)w)[g];
        float4 bv = ((const float4*)bias)[g];
        float4 a4, b4;
        a4.x = inv_std * wv.x; b4.x = bv.x - mean * a4.x;
        a4.y = inv_std * wv.y; b4.y = bv.y - mean * a4.y;
        a4.z = inv_std * wv.z; b4.z = bv.z - mean * a4.z;
        a4.w = inv_std * wv.w; b4.w = bv.w - mean * a4.w;
        lA[b * NGRP + g] = a4;
        lB[b * NGRP + g] = b4;
    }
    __syncthreads();

    const float4* d4 = (const float4*)data;
    float4* o4 = (float4*)out;

    long long i      = (long long)blockIdx.x * blockDim.x + threadIdx.x;
    long long stride = (long long)gridDim.x * blockDim.x;

    for (; i < total4; i += stride) {
        long long j   = total4 - 1 - i;   // reversed global sweep: tail first
        long long row = j >> 4;
        int c4 = (int)(j & 15);
        int b  = bid[row];
        float4 v  = d4[j];
        float4 a  = lA[b * NGRP + c4];
        float4 bb = lB[b * NGRP + c4];
        f32x4 r;
        r.x = fmaf(v.x, a.x, bb.x);
        r.y = fmaf(v.y, a.y, bb.y);
        r.z = fmaf(v.z, a.z, bb.z);
        r.w = fmaf(v.w, a.w, bb.w);
        __builtin_nontemporal_store(r, (f32x4*)&o4[j]);
    }
}

extern "C" void kernel_launch(void* const* d_in, const int* in_sizes, int n_in,
                              void* d_out, int out_size, void* d_ws, size_t ws_size,
                              hipStream_t stream) {
    const float* data = (const float*)d_in[0];
    const int*   bid  = (const int*)d_in[1];
    const float* w    = (const float*)d_in[2];
    const float* bias = (const float*)d_in[3];
    float* out = (float*)d_out;

    int N = in_sizes[1];  // batch_id count

    char* ws = (char*)d_ws;
    float* S1  = (float*)(ws + 0);
    float* S2  = (float*)(ws + 4096);
    int*   cnt = (int*)  (ws + 8192);

    // zero the accumulator region (S1, S2, cnt)
    hipMemsetAsync(d_ws, 0, 8256, stream);

    const int NB1 = 2048;
    int rows_per_block = (N + NB1 - 1) / NB1;
    ogn_stats<<<NB1, 256, 0, stream>>>(data, bid, S1, S2, cnt, N, rows_per_block);

    long long total4 = (long long)N * (NCH / 4);
    const int NB3 = 4096;
    ogn_apply<<<NB3, 256, 0, stream>>>(data, bid, S1, S2, cnt, w, bias, out, total4);
}